// Round 14
// baseline (29.608 us; speedup 1.0000x reference)
//
#include <hip/hip_runtime.h>

// MTGP covariance, round 14: full-matrix compute + row-streamed 1KB stores.
// cov[i,j] = sum_z W[ti,z]W[tj,z]*th[z,0]*exp(-0.5*th[z,1]*||Xi-Xj||^2) + 0.002*I
// M=4096, D=64, Z=4, fp32 in/out.
// pack (R9, verified): X -> Ph/Pl (bf16 hi/lo, MFMA-fragment-ordered) + norms.
// main: 2048 blocks = 128 row-groups (32 rows) x 16 col-groups (256 cols).
//   Wave = 2 row-slabs x 4 col-slabs of 16x16 (swapped-operand MFMA: lane
//   holds 4 consecutive cols of one row). Epilogue -> LDS chunk[32][264].
//   Barrier. Stream phase: each wave stores 8 full rows as 1KB fully
//   contiguous 64-lane dwordx4 stores (fillBuffer's pattern) -> DRAM-page
//   sequential streams. No symmetry/mirror stores. Deterministic.

#define M_PTS 4096
#define DIM 64
#define JITTER_F 0.002f
#define NEG_HALF_LOG2E (-0.72134752044448170f)  // -0.5*log2(e)

typedef __attribute__((ext_vector_type(8))) short short8v;   // 8 bf16
typedef __attribute__((ext_vector_type(4))) float f32x4;

union FragU { short8v v; uint4 u; };

__device__ __forceinline__ float fast_exp2(float x) {
#if defined(__has_builtin)
#if __has_builtin(__builtin_amdgcn_exp2f)
  return __builtin_amdgcn_exp2f(x);
#else
  return exp2f(x);
#endif
#else
  return exp2f(x);
#endif
}

__device__ __forceinline__ unsigned bfr(float x) {  // fp32 -> bf16 (rne), as u16
  unsigned u = __float_as_uint(x);
  return (u + 0x7FFFu + ((u >> 16) & 1u)) >> 16;
}
__device__ __forceinline__ float bff(unsigned h) {  // bf16 bits -> fp32
  return __uint_as_float(h << 16);
}

// ---------------- pack: hi/lo split into fragment order + row norms (R9, verified) ----------------
__global__ __launch_bounds__(256) void mtgp_pack(
    const float* __restrict__ X, unsigned short* __restrict__ Ph,
    unsigned short* __restrict__ Pl, float* __restrict__ sqn) {
  const int t = blockIdx.x * 256 + threadIdx.x;  // 0..8191
  const int row = t >> 1, k0 = t & 1;            // thread owns 32 elems of one row
  const float4* xr = (const float4*)(X + (size_t)row * DIM + k0 * 32);
  float va[32];
  float s = 0.0f;
#pragma unroll
  for (int i = 0; i < 8; ++i) {
    const float4 vv = xr[i];
    va[4 * i + 0] = vv.x; va[4 * i + 1] = vv.y;
    va[4 * i + 2] = vv.z; va[4 * i + 3] = vv.w;
    s = fmaf(vv.x, vv.x, s); s = fmaf(vv.y, vv.y, s);
    s = fmaf(vv.z, vv.z, s); s = fmaf(vv.w, vv.w, s);
  }
  s += __shfl_xor(s, 1);                         // (row,k0=0)+(row,k0=1) pair
  if (k0 == 0) sqn[row] = s;
  const int fbase = ((row >> 4) * 2 + k0) * 512; // frag id * 512 ush
#pragma unroll
  for (int kg = 0; kg < 4; ++kg) {
    unsigned h[8], l[8];
#pragma unroll
    for (int j = 0; j < 4; ++j) {
      const float x0 = va[4 * kg + j], x1 = va[16 + 4 * kg + j];
      h[j] = bfr(x0);     l[j] = bfr(x0 - bff(h[j]));
      h[4 + j] = bfr(x1); l[4 + j] = bfr(x1 - bff(h[4 + j]));
    }
    const uint4 hv = make_uint4(h[0] | (h[1] << 16), h[2] | (h[3] << 16),
                                h[4] | (h[5] << 16), h[6] | (h[7] << 16));
    const uint4 lv = make_uint4(l[0] | (l[1] << 16), l[2] | (l[3] << 16),
                                l[4] | (l[5] << 16), l[6] | (l[7] << 16));
    const int lofs = fbase + (((kg << 4) + (row & 15)) << 3);  // lane*8 ush
    *(uint4*)&Ph[lofs] = hv;
    *(uint4*)&Pl[lofs] = lv;
  }
}

// ---------------- main: 32 rows x 256 cols per block, streamed stores ----------------
__global__ __launch_bounds__(256, 4) void mtgp_stream(
    const unsigned short* __restrict__ Ph, const unsigned short* __restrict__ Pl,
    const float* __restrict__ sqn, const float* __restrict__ W,
    const float* __restrict__ theta, float* __restrict__ out) {
  __shared__ float chunk[32 * 264];              // 33KB, row stride 264 floats

  const int tid = threadIdx.x;
  const int wid = tid >> 6, lane = tid & 63;
  const int rg = blockIdx.x >> 4;                // 0..127 row-group (32 rows)
  const int cg = blockIdx.x & 15;                // 0..15 col-group (256 cols)
  const int row0 = rg << 5;
  const int c0 = cg << 8;
  const int r16 = lane & 15, kg = lane >> 4, kg4 = kg << 2;
  const int l8 = lane << 3;                      // lane ush offset within frag

  // ---- A fragments for the block's 2 row-slabs (held in regs) ----
  FragU ah[2][2], al[2][2];                      // [p][k0]
  const int sa = row0 >> 4;
#pragma unroll
  for (int p = 0; p < 2; ++p)
#pragma unroll
    for (int k0 = 0; k0 < 2; ++k0) {
      const int fb = ((sa + p) * 2 + k0) * 512 + l8;
      ah[p][k0].u = *(const uint4*)&Ph[fb];
      al[p][k0].u = *(const uint4*)&Pl[fb];
    }
  float sqr[2];
  sqr[0] = sqn[row0 + r16];                      // lane's output row, slab 0
  sqr[1] = sqn[row0 + 16 + r16];                 // slab 1

  // ---- mixing coefficients (block-constant) ----
  const int ti = row0 >> 10, tj = c0 >> 10;
  float czv[4], ezv[4];
#pragma unroll
  for (int z = 0; z < 4; ++z) {
    czv[z] = W[ti * 4 + z] * W[tj * 4 + z] * theta[2 * z];
    ezv[z] = NEG_HALF_LOG2E * theta[2 * z + 1];
  }

  // ---- compute: wave covers cols [c0+wid*64, +64) = 4 slabs x 2 row-slabs ----
#pragma unroll 1
  for (int s = 0; s < 4; ++s) {
    const int v = (c0 >> 4) + (wid << 2) + s;    // global col slab
    const int fb = (v * 2) * 512 + l8;
    FragU bh0, bl0, bh1, bl1;
    bh0.u = *(const uint4*)&Ph[fb];
    bl0.u = *(const uint4*)&Pl[fb];
    bh1.u = *(const uint4*)&Ph[fb + 512];
    bl1.u = *(const uint4*)&Pl[fb + 512];
    const f32x4 sqc = *(const f32x4*)&sqn[v * 16 + kg4];

#pragma unroll
    for (int p = 0; p < 2; ++p) {
      f32x4 acc = (f32x4)0.0f;
      // swapped operands: lane holds out[row0+p*16+r16][v*16+kg4+rr]
      acc = __builtin_amdgcn_mfma_f32_16x16x32_bf16(bh0.v, ah[p][0].v, acc, 0, 0, 0);
      acc = __builtin_amdgcn_mfma_f32_16x16x32_bf16(bh0.v, al[p][0].v, acc, 0, 0, 0);
      acc = __builtin_amdgcn_mfma_f32_16x16x32_bf16(bl0.v, ah[p][0].v, acc, 0, 0, 0);
      acc = __builtin_amdgcn_mfma_f32_16x16x32_bf16(bh1.v, ah[p][1].v, acc, 0, 0, 0);
      acc = __builtin_amdgcn_mfma_f32_16x16x32_bf16(bh1.v, al[p][1].v, acc, 0, 0, 0);
      acc = __builtin_amdgcn_mfma_f32_16x16x32_bf16(bl1.v, ah[p][1].v, acc, 0, 0, 0);

      const int orow = p * 16 + r16;             // block-relative row
      f32x4 res;
#pragma unroll
      for (int rr = 0; rr < 4; ++rr) {
        const float sd = fmaxf(fmaf(-2.0f, acc[rr], sqr[p] + sqc[rr]), 0.0f);
        float val = czv[0] * fast_exp2(ezv[0] * sd);
        val = fmaf(czv[1], fast_exp2(ezv[1] * sd), val);
        val = fmaf(czv[2], fast_exp2(ezv[2] * sd), val);
        val = fmaf(czv[3], fast_exp2(ezv[3] * sd), val);
        if (row0 + orow == v * 16 + kg4 + rr) val += JITTER_F;  // global diag
        res[rr] = val;
      }
      *(f32x4*)&chunk[orow * 264 + (wid << 6) + (s << 4) + kg4] = res;
    }
  }
  __syncthreads();

  // ---- stream store: wave w -> rows 8w..8w+7; 1KB fully contiguous per instr ----
#pragma unroll
  for (int i = 0; i < 8; ++i) {
    const int row = (wid << 3) + i;
    const f32x4 vv = *(const f32x4*)&chunk[row * 264 + (lane << 2)];
    *(f32x4*)&out[(size_t)(row0 + row) * M_PTS + c0 + (lane << 2)] = vv;
  }
}

extern "C" void kernel_launch(void* const* d_in, const int* in_sizes, int n_in,
                              void* d_out, int out_size, void* d_ws, size_t ws_size,
                              hipStream_t stream) {
  const float* x     = (const float*)d_in[0];   // (4,1024,64)
  const float* W     = (const float*)d_in[1];   // (4,4)
  const float* theta = (const float*)d_in[2];   // (4,2)
  float* out = (float*)d_out;                   // (4096,4096)

  // workspace: sqn (16 KB) | Ph (512 KB) | Pl (512 KB)
  float* sqn = (float*)d_ws;
  unsigned short* Ph = (unsigned short*)((char*)d_ws + 16384);
  unsigned short* Pl = (unsigned short*)((char*)d_ws + 16384 + 524288);

  mtgp_pack<<<dim3(32), dim3(256), 0, stream>>>(x, Ph, Pl, sqn);
  mtgp_stream<<<dim3(2048), dim3(256), 0, stream>>>(Ph, Pl, sqn, W, theta, out);
}

// Round 15
// 24.280 us; speedup vs baseline: 1.2195x; 1.2195x over previous
//
#include <hip/hip_runtime.h>

// MTGP covariance — FINAL (restore of round-7 best: 24.29 µs).
// cov[i,j] = sum_z W[ti,z]W[tj,z]*th[z,0]*exp(-0.5*th[z,1]*||Xi-Xj||^2) + 0.002*I
// M=4096, D=64, Z=4, fp32 in/out. Single fused kernel.
// 2080 upper-tri 64x64 tiles, 4 waves (2x2 grid of 32x32). Per block:
//  - stage fp32 X rows -> in-register bf16 hi/lo split -> k-permuted,
//    XOR-swizzled LDS panels (32 KB exactly -> 5 blocks/CU)
//  - row norms via paired-lane shuffle, published into dead panel LDS
//  - K-loop: 16 ds_read_b128 frags + 24 mfma_f32_16x16x32_bf16 (hh+hl+lh)
//  - fused RBF epilogue; direct + (off-diag) transpose stores, exact-once.
// Roofline note: kernel ~20.5 µs = 67.1 MB output / ~3.2 TB/s, the measured
// computed-store write ceiling (m13 float4-copy write component ~3.15 TB/s).
// Store-pattern axes (width/nt/streaming), TLP, barriers, pipelining all
// experimentally nulled in rounds 8-14.

#define M_PTS 4096
#define DIM 64
#define JITTER_F 0.002f
#define NEG_HALF_LOG2E (-0.72134752044448170f)  // -0.5*log2(e)
#define NBLK 2080                                // 64*65/2

typedef __attribute__((ext_vector_type(8))) short short8v;   // 8 bf16
typedef __attribute__((ext_vector_type(4))) float f32x4;

union FragU { short8v v; uint4 u; };

__device__ __forceinline__ float fast_exp2(float x) {
#if defined(__has_builtin)
#if __has_builtin(__builtin_amdgcn_exp2f)
  return __builtin_amdgcn_exp2f(x);
#else
  return exp2f(x);
#endif
#else
  return exp2f(x);
#endif
}

__device__ __forceinline__ unsigned bfr(float x) {  // fp32 -> bf16 (rne), as u16
  unsigned u = __float_as_uint(x);
  return (u + 0x7FFFu + ((u >> 16) & 1u)) >> 16;
}
__device__ __forceinline__ float bff(unsigned h) {  // bf16 bits -> fp32
  return __uint_as_float(h << 16);
}

__global__ __launch_bounds__(256, 5) void mtgp_fused(
    const float* __restrict__ X,      // [4096,64]
    const float* __restrict__ W,      // [4,4]
    const float* __restrict__ theta,  // [4,2]
    float* __restrict__ out) {        // [4096,4096]
  // Panels: row r, 16B slot f stored at ush offset r*64 + ((f ^ (r&7))<<3).
  __shared__ unsigned short Ahi[64 * 64], Alo[64 * 64];  // 8KB each
  __shared__ unsigned short Bhi[64 * 64], Blo[64 * 64];  // 8KB each (32KB total)

  // ---- decode item -> (u, v), v >= u, 64 slabs; prefix(u) = u*(129-u)/2 ----
  const int item = blockIdx.x;
  int u = (int)(64.5f - sqrtf(4160.25f - 2.0f * (float)item));
  if (u < 0) u = 0;
  if (u > 63) u = 63;
  while (u > 0 && u * (129 - u) / 2 > item) --u;
  while (u < 63 && (u + 1) * (128 - u) / 2 <= item) ++u;
  const int v = u + (item - u * (129 - u) / 2);
  const int grow0 = u << 6, gj0 = v << 6;

  const int tid = threadIdx.x;

  // ---- fused staging: fp32 -> hi/lo split -> k-permuted swizzled LDS ----
  // thread t: panel = (t<128 ? A : B), row = (t&127)>>1, half = t&1 (32 floats)
  const int half = tid & 1;
  const int srow = (tid & 127) >> 1;
  const bool isB = (tid >= 128);
  const int gsrow = (isB ? gj0 : grow0) + srow;
  const float4* xr = (const float4*)(X + (size_t)gsrow * DIM + half * 32);
  unsigned short* Ph = isB ? Bhi : Ahi;
  unsigned short* Pl = isB ? Blo : Alo;
  float s = 0.0f;  // row-half norm partial (fixed order -> deterministic)
#pragma unroll
  for (int kgs = 0; kgs < 4; ++kgs) {
    const float4 v0 = xr[kgs];        // locals 4k..4k+3
    const float4 v1 = xr[kgs + 4];    // locals 16+4k..16+4k+3
    s = fmaf(v0.x, v0.x, s); s = fmaf(v0.y, v0.y, s);
    s = fmaf(v0.z, v0.z, s); s = fmaf(v0.w, v0.w, s);
    s = fmaf(v1.x, v1.x, s); s = fmaf(v1.y, v1.y, s);
    s = fmaf(v1.z, v1.z, s); s = fmaf(v1.w, v1.w, s);
    const unsigned h0 = bfr(v0.x), h1 = bfr(v0.y), h2 = bfr(v0.z), h3 = bfr(v0.w);
    const unsigned h4 = bfr(v1.x), h5 = bfr(v1.y), h6 = bfr(v1.z), h7 = bfr(v1.w);
    uint4 hv = make_uint4(h0 | (h1 << 16), h2 | (h3 << 16),
                          h4 | (h5 << 16), h6 | (h7 << 16));
    const unsigned l0 = bfr(v0.x - bff(h0)), l1 = bfr(v0.y - bff(h1));
    const unsigned l2 = bfr(v0.z - bff(h2)), l3 = bfr(v0.w - bff(h3));
    const unsigned l4 = bfr(v1.x - bff(h4)), l5 = bfr(v1.y - bff(h5));
    const unsigned l6 = bfr(v1.z - bff(h6)), l7 = bfr(v1.w - bff(h7));
    uint4 lv = make_uint4(l0 | (l1 << 16), l2 | (l3 << 16),
                          l4 | (l5 << 16), l6 | (l7 << 16));
    const int f = (half << 2) + kgs;
    const int lofs = srow * 64 + ((f ^ (srow & 7)) << 3);
    *(uint4*)&Ph[lofs] = hv;
    *(uint4*)&Pl[lofs] = lv;
  }
  s += __shfl_xor(s, 1);  // pair (t, t^1) = two halves of the same row
  __syncthreads();

  const int wid = tid >> 6, lane = tid & 63;
  const int wr = (wid >> 1) << 5;          // wave row offset (0/32)
  const int wc = (wid & 1) << 5;           // wave col offset (0/32)
  const int r16 = lane & 15, kg = lane >> 4, kg4 = kg << 2;

  f32x4 acc[2][2];
#pragma unroll
  for (int p = 0; p < 2; ++p) { acc[p][0] = (f32x4)0.0f; acc[p][1] = (f32x4)0.0f; }

  // frag: lane (kg,r16) reads 16B slot f0 = k0*4+kg of row rr (one b128)
#define FRAG_LD(dst, PANEL, rr) { \
    dst.u = *(const uint4*)&PANEL[(rr) * 64 + ((f0 ^ ((rr) & 7)) << 3)]; }

#pragma unroll
  for (int k0 = 0; k0 < 2; ++k0) {
    const int f0 = (k0 << 2) + kg;
    FragU ah[2], al[2], bh[2], bl[2];
#pragma unroll
    for (int p = 0; p < 2; ++p) {
      const int ra = wr + p * 16 + r16;
      const int rb = wc + p * 16 + r16;
      FRAG_LD(ah[p], Ahi, ra)
      FRAG_LD(al[p], Alo, ra)
      FRAG_LD(bh[p], Bhi, rb)
      FRAG_LD(bl[p], Blo, rb)
    }
#pragma unroll
    for (int p = 0; p < 2; ++p)
#pragma unroll
      for (int q = 0; q < 2; ++q) {
        acc[p][q] = __builtin_amdgcn_mfma_f32_16x16x32_bf16(ah[p].v, bh[q].v, acc[p][q], 0, 0, 0);
        acc[p][q] = __builtin_amdgcn_mfma_f32_16x16x32_bf16(ah[p].v, bl[q].v, acc[p][q], 0, 0, 0);
        acc[p][q] = __builtin_amdgcn_mfma_f32_16x16x32_bf16(al[p].v, bh[q].v, acc[p][q], 0, 0, 0);
      }
  }
#undef FRAG_LD

  // ---- publish row norms into dead panel LDS ----
  __syncthreads();                         // all frag reads complete
  if (half == 0) ((float*)Ahi)[(isB ? 64 : 0) + srow] = s;
  __syncthreads();
  const float* nrm = (const float*)Ahi;    // [0..63]=A rows, [64..127]=B rows

  // ---- epilogue ----
  const int ti = u >> 4, tj = v >> 4;      // 16 slabs of 64 rows per task
  float czv[4], ezv[4];
#pragma unroll
  for (int z = 0; z < 4; ++z) {
    czv[z] = W[ti * 4 + z] * W[tj * 4 + z] * theta[2 * z];
    ezv[z] = NEG_HALF_LOG2E * theta[2 * z + 1];
  }
  f32x4 sqr[2];
#pragma unroll
  for (int p = 0; p < 2; ++p) sqr[p] = *(const f32x4*)&nrm[wr + p * 16 + kg4];
  float sqc[2];
#pragma unroll
  for (int q = 0; q < 2; ++q) sqc[q] = nrm[64 + wc + q * 16 + r16];

#pragma unroll
  for (int p = 0; p < 2; ++p)
#pragma unroll
    for (int q = 0; q < 2; ++q)
#pragma unroll
      for (int rr = 0; rr < 4; ++rr) {
        const float d = acc[p][q][rr];
        const float sd = fmaxf(fmaf(-2.0f, d, sqr[p][rr] + sqc[q]), 0.0f);
        float val = czv[0] * fast_exp2(ezv[0] * sd);
        val = fmaf(czv[1], fast_exp2(ezv[1] * sd), val);
        val = fmaf(czv[2], fast_exp2(ezv[2] * sd), val);
        val = fmaf(czv[3], fast_exp2(ezv[3] * sd), val);
        if (u == v && wr + p * 16 + kg4 + rr == wc + q * 16 + r16) val += JITTER_F;
        acc[p][q][rr] = val;
      }

  // ---- direct store: rows grow0+wr.., cols gj0+wc.. ----
#pragma unroll
  for (int p = 0; p < 2; ++p)
#pragma unroll
    for (int rr = 0; rr < 4; ++rr) {
      float* rp = out + (size_t)(grow0 + wr + p * 16 + kg4 + rr) * M_PTS + gj0 + wc + r16;
      rp[0] = acc[p][0][rr];
      rp[16] = acc[p][1][rr];
    }
  // ---- transpose store (off-diagonal only): mirror to strictly-below region ----
  if (u != v) {
#pragma unroll
    for (int q = 0; q < 2; ++q)
#pragma unroll
      for (int p = 0; p < 2; ++p) {
        f32x4* tp = (f32x4*)(out + (size_t)(gj0 + wc + q * 16 + r16) * M_PTS + grow0 + wr + p * 16 + kg4);
        *tp = acc[p][q];
      }
  }
}

extern "C" void kernel_launch(void* const* d_in, const int* in_sizes, int n_in,
                              void* d_out, int out_size, void* d_ws, size_t ws_size,
                              hipStream_t stream) {
  const float* x     = (const float*)d_in[0];   // (4,1024,64)
  const float* W     = (const float*)d_in[1];   // (4,4)
  const float* theta = (const float*)d_in[2];   // (4,2)
  float* out = (float*)d_out;                   // (4096,4096)

  mtgp_fused<<<dim3(NBLK), dim3(256), 0, stream>>>(x, W, theta, out);
}